// Round 6
// baseline (296.278 us; speedup 1.0000x reference)
//
#include <hip/hip_runtime.h>
#include <stdint.h>

// ---------------------------------------------------------------------------
// LongSelfAttention: x[16384,1024] -> QKV proj -> per-token 16x16 head attn
// -> O proj.
// GEMMs: 256x256 tile, BK=64, 8 waves (2Mx4N). THIS REV: ONE barrier per
// K-tile (was 4). Per tile: {stage 4 halves of t+1 ; read all 24 frags of t ;
// 64 MFMAs ; lgkm(0) ; vmcnt(0) ; SBAR}. Waves free-run across the tile so
// the LDS port (≈2800 cy/tile: 192 b128 reads + 64KB DMA) serves one wave's
// reads under other waves' MFMAs (≈2483 cy/tile). Round 4/5 counters proved
// 4-barrier phases kept these serial (5080 cy/tile, MfmaUtil 40-43%).
// Hazards: RAW stage(t+1)->reads(t+1) gated by vmcnt(0)+SBAR at tile end
// (stages had the whole tile to land; wait ~free). WAR stage(t+1) vs
// reads(t-1, same buffer) gated by tile-(t-1)'s lgkm(0)+SBAR (stages issue
// post-SBAR). LDS XOR-swizzle (T2), setprio (T5), XCD swizzle (T1),
// persistent QKV grid (256 blocks x 3 matrices) unchanged.
// Workspace layout (bytes):
//   [0,            32 MiB) x_bf16           [16384][1024]
//   [32 MiB,       40 MiB) W^T bf16 x4      [4][1024][1024]  (q,k,v,o)
//   [40 MiB,      136 MiB) qkv bf16         [3][16384][1024]  (attn overwrites q)
// ---------------------------------------------------------------------------

typedef __attribute__((ext_vector_type(8))) short short8;
typedef __attribute__((ext_vector_type(4))) float floatx4;
typedef __attribute__((address_space(1))) unsigned int gu32;
typedef __attribute__((address_space(3))) unsigned int lu32;

#define HID 1024
#define MTOK 16384                 // B*L
#define WELEM (HID * HID)          // 1048576
#define XELEM (MTOK * HID)         // 16777216

#define SBAR() __builtin_amdgcn_s_barrier()
// rule #18: pin subsequent code below the wait with a sched_barrier
#define WAITLGKM() do { asm volatile("s_waitcnt lgkmcnt(0)" ::: "memory"); \
                        __builtin_amdgcn_sched_barrier(0); } while (0)
#define VMCNT(n) do { asm volatile("s_waitcnt vmcnt(" #n ")" ::: "memory"); \
                      __builtin_amdgcn_sched_barrier(0); } while (0)

__device__ __forceinline__ unsigned short f2bf(float f) {
  union { float f; uint32_t u; } v; v.f = f;
  uint32_t u = v.u;
  u += 0x7fffu + ((u >> 16) & 1u);   // round-to-nearest-even
  return (unsigned short)(u >> 16);
}

// ---- x fp32 -> bf16, vectorized -------------------------------------------
__global__ __launch_bounds__(256) void cvt_x_kernel(const float* __restrict__ x,
                                                    unsigned short* __restrict__ xb) {
  const int idx = blockIdx.x * 256 + threadIdx.x;
  float4 v = ((const float4*)x)[idx];
  ushort4 o;
  o.x = f2bf(v.x); o.y = f2bf(v.y); o.z = f2bf(v.z); o.w = f2bf(v.w);
  ((ushort4*)xb)[idx] = o;
}

// ---- W [k][n] fp32 -> W^T [n][k] bf16 via 64x64 LDS tile ------------------
__global__ __launch_bounds__(256) void cvt_w_kernel(const float* __restrict__ W0,
                                                    const float* __restrict__ W1,
                                                    const float* __restrict__ W2,
                                                    const float* __restrict__ W3,
                                                    unsigned short* __restrict__ WT) {
  const float* W = (blockIdx.z == 0) ? W0 : (blockIdx.z == 1) ? W1
                   : (blockIdx.z == 2) ? W2 : W3;
  unsigned short* out = WT + (size_t)blockIdx.z * WELEM;
  __shared__ float tile[64][65];
  const int t = threadIdx.x;
  const int n0 = blockIdx.x * 64, k0 = blockIdx.y * 64;
#pragma unroll
  for (int i = 0; i < 4; i++) {
    const int row = i * 16 + (t >> 4);     // k within tile
    const int col = (t & 15) * 4;          // n within tile
    float4 v = *(const float4*)&W[(size_t)(k0 + row) * HID + n0 + col];
    tile[row][col] = v.x; tile[row][col + 1] = v.y;
    tile[row][col + 2] = v.z; tile[row][col + 3] = v.w;
  }
  __syncthreads();
#pragma unroll
  for (int i = 0; i < 4; i++) {
    const int n = i * 16 + (t >> 4);
    const int k = (t & 15) * 4;
    ushort4 o;
    o.x = f2bf(tile[k][n]);     o.y = f2bf(tile[k + 1][n]);
    o.z = f2bf(tile[k + 2][n]); o.w = f2bf(tile[k + 3][n]);
    *(ushort4*)&out[(size_t)(n0 + n) * HID + k0 + k] = o;
  }
}

// ---------------------------------------------------------------------------
// 256x256x(BK=64) NT GEMM, one barrier per K-tile (see header comment).
// ---------------------------------------------------------------------------
template <bool QKV>
__global__ __launch_bounds__(512, 2) void gemm256(
    const unsigned short* __restrict__ A,     // [MTOK][HID] bf16
    const unsigned short* __restrict__ BTb,   // base of W^T array
    const float* __restrict__ b0, const float* __restrict__ b1,
    const float* __restrict__ b2,
    void* __restrict__ Cv)
{
  __shared__ short8 smem_[131072 / 16];      // 128 KiB
  char* smem = (char*)smem_;

  constexpr int R = QKV ? 3 : 1;
  const int bid = blockIdx.x;
  const int xcd = bid & 7;
  const int j = bid >> 3;                    // 0..31
  const int nb0 = j >> 3;                    // 0..3
  const int mb = xcd * 8 + (j & 7);          // 0..63 (m-band per XCD, fixed)
  const int m0 = mb * 256;
  const int cb = nb0 * 256;                  // output col base (per-matrix)

  const unsigned short* BT0 = QKV ? BTb : (BTb + (size_t)3 * WELEM);

  const int t_ = threadIdx.x;
  const int wv = t_ >> 6, lane = t_ & 63;
  const int quad = lane >> 4, r16 = lane & 15;
  const int wm = wv >> 2, wn = wv & 3;

  // staging source (per-lane; k-chunk pre-permuted to compensate swizzle)
  const int srow = wv * 16 + (lane >> 2);
  const int scol = ((lane & 3) ^ ((lane >> 3) & 3)) * 8;
  const unsigned short* Ag = A + (size_t)(m0 + srow) * HID + scol;
  const unsigned short* Bg = BT0 + (size_t)(cb + srow) * HID + scol;

  // ds_read bases (swizzled): byte = base + ks*8192 + frag*1024
  const int qsw = (quad ^ ((r16 >> 1) & 3)) << 4;
  const char* Ard = smem + wm * 16384 + r16 * 64 + qsw;
  const char* Brd = smem + 32768 + (wn >> 1) * 16384 + ((wn & 1) * 64 + r16) * 64 + qsw;

  floatx4 acc[8][4] = {};

  // stage half h of K-tile tt into buffer tt&1 (LDS dest linear, rule #21)
  auto stageA = [&](int h, int tt) {
    const unsigned short* s = Ag + (size_t)h * 128 * HID + tt * 64;
    char* d = smem + ((tt & 1) << 16) + h * 16384 + wv * 1024;
    __builtin_amdgcn_global_load_lds((const gu32*)s,        (lu32*)d,          16, 0, 0);
    __builtin_amdgcn_global_load_lds((const gu32*)(s + 32), (lu32*)(d + 8192), 16, 0, 0);
  };
  auto stageB = [&](int h, int tt) {
    const unsigned short* s = Bg + (size_t)h * 128 * HID + tt * 64;
    char* d = smem + ((tt & 1) << 16) + 32768 + h * 16384 + wv * 1024;
    __builtin_amdgcn_global_load_lds((const gu32*)s,        (lu32*)d,          16, 0, 0);
    __builtin_amdgcn_global_load_lds((const gu32*)(s + 32), (lu32*)(d + 8192), 16, 0, 0);
  };

  const int NT = HID / 64;                   // 16 K-tiles (even)

  short8 alo[4][2], ahi[4][2];               // A fragments
  short8 b01[2][2], b23[2][2];               // B fragments

  // prologue: stage tile 0, drain, barrier
  stageA(0, 0); stageA(1, 0); stageB(0, 0); stageB(1, 0);
  VMCNT(0);
  SBAR();

  for (int r = 0; r < R; ++r) {
    for (int t = 0; t < NT; ++t) {
      const int bufb = (t & 1) << 16;
      const bool more = (t + 1 < NT);

      // -- stage all 4 halves of t+1 (fly across this whole tile) ----------
      if (more) { stageA(0, t + 1); stageA(1, t + 1);
                  stageB(0, t + 1); stageB(1, t + 1); }

      // -- read all 24 frags of tile t (order matches first MFMA consumers) -
#pragma unroll
      for (int ks = 0; ks < 2; ++ks)
#pragma unroll
        for (int mi = 0; mi < 4; ++mi)
          alo[mi][ks] = *(const short8*)(Ard + bufb + ks * 8192 + mi * 1024);
#pragma unroll
      for (int ks = 0; ks < 2; ++ks)
#pragma unroll
        for (int ni = 0; ni < 2; ++ni)
          b01[ni][ks] = *(const short8*)(Brd + bufb + ks * 8192 + ni * 1024);
#pragma unroll
      for (int ks = 0; ks < 2; ++ks)
#pragma unroll
        for (int ni = 0; ni < 2; ++ni)
          b23[ni][ks] = *(const short8*)(Brd + bufb + ks * 8192 + (2 + ni) * 1024);
#pragma unroll
      for (int ks = 0; ks < 2; ++ks)
#pragma unroll
        for (int mi = 0; mi < 4; ++mi)
          ahi[mi][ks] = *(const short8*)(Ard + bufb + ks * 8192 + (4 + mi) * 1024);

      // -- 64 MFMAs; compiler interleaves counted lgkmcnt with the reads ----
      __builtin_amdgcn_s_setprio(1);
#pragma unroll
      for (int ks = 0; ks < 2; ++ks)
#pragma unroll
        for (int mi = 0; mi < 4; ++mi)
#pragma unroll
          for (int ni = 0; ni < 2; ++ni)
            acc[mi][ni] = __builtin_amdgcn_mfma_f32_16x16x32_bf16(alo[mi][ks], b01[ni][ks], acc[mi][ni], 0, 0, 0);
#pragma unroll
      for (int ks = 0; ks < 2; ++ks)
#pragma unroll
        for (int mi = 0; mi < 4; ++mi)
#pragma unroll
          for (int ni = 0; ni < 2; ++ni)
            acc[mi][2 + ni] = __builtin_amdgcn_mfma_f32_16x16x32_bf16(alo[mi][ks], b23[ni][ks], acc[mi][2 + ni], 0, 0, 0);
#pragma unroll
      for (int ks = 0; ks < 2; ++ks)
#pragma unroll
        for (int mi = 0; mi < 4; ++mi)
#pragma unroll
          for (int ni = 0; ni < 2; ++ni)
            acc[4 + mi][2 + ni] = __builtin_amdgcn_mfma_f32_16x16x32_bf16(ahi[mi][ks], b23[ni][ks], acc[4 + mi][2 + ni], 0, 0, 0);
#pragma unroll
      for (int ks = 0; ks < 2; ++ks)
#pragma unroll
        for (int mi = 0; mi < 4; ++mi)
#pragma unroll
          for (int ni = 0; ni < 2; ++ni)
            acc[4 + mi][ni] = __builtin_amdgcn_mfma_f32_16x16x32_bf16(ahi[mi][ks], b01[ni][ks], acc[4 + mi][ni], 0, 0, 0);
      __builtin_amdgcn_s_setprio(0);

      // -- tile-end fence: own reads drained; t+1 stages landed; barrier ----
      WAITLGKM();
      VMCNT(0);
      SBAR();
    }

    // issue next matrix's tile-0 stages before the epilogue stores
    if (r + 1 < R) {
      Bg += WELEM;                           // next weight matrix (z = r+1)
      stageA(0, 0); stageA(1, 0); stageB(0, 0); stageB(1, 0);
    }

    // epilogue: C/D layout col=lane&15, row=quad*4+reg (measured m89/m91)
    {
      const float* bias = QKV ? ((r == 0) ? b0 : ((r == 1) ? b1 : b2)) : b0;
      float bvv[4];
#pragma unroll
      for (int ni = 0; ni < 4; ++ni) bvv[ni] = bias[cb + wn * 64 + ni * 16 + r16];

      const int row0 = m0 + wm * 128 + quad * 4;
      unsigned short* outb = (unsigned short*)Cv + (size_t)r * XELEM;
      float* outf = (float*)Cv;
#pragma unroll
      for (int mi = 0; mi < 8; ++mi) {
#pragma unroll
        for (int rr = 0; rr < 4; ++rr) {
          const size_t roff = (size_t)(row0 + mi * 16 + rr) * HID + cb + wn * 64 + r16;
#pragma unroll
          for (int ni = 0; ni < 4; ++ni) {
            const float val = acc[mi][ni][rr] + bvv[ni];
            if constexpr (QKV) outb[roff + ni * 16] = f2bf(val);
            else               outf[roff + ni * 16] = val;
          }
        }
      }
    }

    if (r + 1 < R) {
      // zero acc, drain stages (+stores), barrier before next matrix's reads
#pragma unroll
      for (int mi = 0; mi < 8; ++mi)
#pragma unroll
        for (int ni = 0; ni < 4; ++ni)
          acc[mi][ni] = floatx4{0.f, 0.f, 0.f, 0.f};
      VMCNT(0);
      SBAR();
    }
  }
}

// ---- per-token head attention: one wave per token, all-MFMA ---------------
__global__ __launch_bounds__(256) void attn_kernel(const unsigned short* qkv,
                                                   unsigned short* attn) {
  __shared__ unsigned short vls[4][1056];    // per wave: rows0-7 @0, rows8-15 @528
  __shared__ unsigned short pls[4][16 * 24]; // P bf16, stride 24 ushorts (48B)

  const int t = threadIdx.x;
  const int wv = t >> 6, lane = t & 63;
  const int quad = lane >> 4, r16 = lane & 15;
  const size_t base = ((size_t)blockIdx.x * 4 + wv) * HID;
  const unsigned short* qp = qkv + base;                     // q[16][64]
  const unsigned short* kp = qkv + (size_t)XELEM + base;     // k[16][64]
  const unsigned short* vp = qkv + 2 * (size_t)XELEM + base; // v[16][64]

  __builtin_amdgcn_global_load_lds((const gu32*)(vp + lane * 8),       (lu32*)&vls[wv][0],   16, 0, 0);
  __builtin_amdgcn_global_load_lds((const gu32*)(vp + 512 + lane * 8), (lu32*)&vls[wv][528], 16, 0, 0);

  short8 qf0 = *(const short8*)(qp + r16 * 64 + quad * 8);
  short8 qf1 = *(const short8*)(qp + r16 * 64 + quad * 8 + 32);
  short8 kf0 = *(const short8*)(kp + r16 * 64 + quad * 8);
  short8 kf1 = *(const short8*)(kp + r16 * 64 + quad * 8 + 32);

  floatx4 sc = {0.f, 0.f, 0.f, 0.f};
  sc = __builtin_amdgcn_mfma_f32_16x16x32_bf16(qf0, kf0, sc, 0, 0, 0);
  sc = __builtin_amdgcn_mfma_f32_16x16x32_bf16(qf1, kf1, sc, 0, 0, 0);

#pragma unroll
  for (int rr = 0; rr < 4; rr++) {
    float s = sc[rr] * 0.125f;
    float m = s;
#pragma unroll
    for (int off = 1; off < 16; off <<= 1) m = fmaxf(m, __shfl_xor(m, off));
    float ex = __expf(s - m);
    float sum = ex;
#pragma unroll
    for (int off = 1; off < 16; off <<= 1) sum += __shfl_xor(sum, off);
    pls[wv][(quad * 4 + rr) * 24 + r16] = f2bf(ex / sum);   // P[h][e]
  }

  __syncthreads();   // covers V DMA completion + cross-lane P visibility

  const short8 zero8 = {0, 0, 0, 0, 0, 0, 0, 0};
  short8 af = zero8;
  short8 bf[4] = {zero8, zero8, zero8, zero8};
  if (quad < 2) {
    af = *(const short8*)&pls[wv][r16 * 24 + quad * 8];
#pragma unroll
    for (int c = 0; c < 4; c++)
#pragma unroll
      for (int jj = 0; jj < 8; jj++)
        bf[c][jj] = (short)vls[wv][quad * 528 + jj * 64 + c * 16 + r16];
  }

  floatx4 ov[4];
#pragma unroll
  for (int c = 0; c < 4; c++) {
    floatx4 z = {0.f, 0.f, 0.f, 0.f};
    ov[c] = __builtin_amdgcn_mfma_f32_16x16x32_bf16(af, bf[c], z, 0, 0, 0);
  }

#pragma unroll
  for (int rr = 0; rr < 4; rr++)
#pragma unroll
    for (int c = 0; c < 4; c++)
      attn[base + (size_t)(quad * 4 + rr) * 64 + c * 16 + r16] = f2bf(ov[c][rr]);
}

extern "C" void kernel_launch(void* const* d_in, const int* in_sizes, int n_in,
                              void* d_out, int out_size, void* d_ws, size_t ws_size,
                              hipStream_t stream) {
  const float* x  = (const float*)d_in[0];
  const float* Wq = (const float*)d_in[1];
  const float* bq = (const float*)d_in[2];
  const float* Wk = (const float*)d_in[3];
  const float* bk = (const float*)d_in[4];
  const float* Wv = (const float*)d_in[5];
  const float* bv = (const float*)d_in[6];
  const float* Wo = (const float*)d_in[7];
  const float* bo = (const float*)d_in[8];

  char* ws = (char*)d_ws;
  unsigned short* xb  = (unsigned short*)ws;                        // 32 MiB
  unsigned short* wt  = (unsigned short*)(ws + (size_t)XELEM * 2);  // 8 MiB
  unsigned short* qkv = wt + 4 * (size_t)WELEM;                     // 96 MiB

  cvt_x_kernel<<<XELEM / 1024, 256, 0, stream>>>(x, xb);
  cvt_w_kernel<<<dim3(16, 16, 4), 256, 0, stream>>>(Wq, Wk, Wv, Wo, wt);
  gemm256<true><<<256, 512, 0, stream>>>(xb, wt, bq, bk, bv, (void*)qkv);
  attn_kernel<<<4096, 256, 0, stream>>>(qkv, qkv);  // attn overwrites q region
  gemm256<false><<<256, 512, 0, stream>>>(qkv, wt, bo, bo, bo, d_out);
}